// Round 5
// baseline (235.277 us; speedup 1.0000x reference)
//
#include <hip/hip_runtime.h>
#include <hip/hip_bf16.h>

// B=32, S=1024, C=D=512 attention, fp32 in/out.
//   1. convert: x -> bf16; [Wq*scale | Wk | Wv] -> bf16 (1536x512)
//   2. gemm_bt<QKV>: Q,K,V^T in ONE dispatch (z in {0,1,2} via decode)
//   3. gemm_bt<EXP>: E = exp(Q K^T) per batch (no max-sub: |s| <= ~1.3, safe)
//      epilogue also writes per-row partial sums psum[row][ytile]
//   4. invsum: invl[row] = 1 / sum_t psum[row][t]
//   5. gemm_bt<PVN>: out = (E V) * invl[row]  (B operand = V^T)
//
// GEMM core: R1's m97-style 128x128 tile, BK=64, 4 waves, global_load_lds
// width 16, XOR-swizzled LDS (pre-swizzled global source). Block mapping:
// capacity-exact XCD supertiles — each XCD (hw: linear_id % 8) gets
// 32-block supertiles (= its concurrent capacity) whose operand panels fit
// its private 4 MiB L2 (R4's 48-block misfit replaced by exact 32).

typedef __attribute__((ext_vector_type(8))) short short8;
typedef __attribute__((ext_vector_type(4))) float f32x4;

#define GLD16(g, l)                                                         \
  __builtin_amdgcn_global_load_lds(                                         \
      (const __attribute__((address_space(1))) void*)(g),                   \
      (__attribute__((address_space(3))) void*)(l), 16, 0, 0)

__device__ __forceinline__ unsigned short f2bf(float f) {
  unsigned int u = __float_as_uint(f);
  u += 0x7fffu + ((u >> 16) & 1u);  // round-to-nearest-even
  return (unsigned short)(u >> 16);
}

enum { ST_QKV = 0, ST_EXP = 1, ST_PVN = 2 };

// Fixed shapes per variant:
//  QKV: A=xb [32768x512], B=wb [1536x512], K=512. grid 3072 (256x * 4y * 3z)
//  EXP: A=qb+z*512K, B=kb+z*512K, K=512, C=sb [1024x1024]/batch. grid 2048
//  PVN: A=sb [1024x1024], B=vtb [512x1024], K=1024, C=out. grid 1024
template <int STORE>
__global__ __launch_bounds__(256) void gemm_bt(
    const unsigned short* __restrict__ A, const unsigned short* __restrict__ B,
    void* __restrict__ Cout, float* __restrict__ psum,
    const float* __restrict__ invl, unsigned short* __restrict__ qd,
    unsigned short* __restrict__ kd, unsigned short* __restrict__ vd) {
  __shared__ unsigned short As[128 * 64];
  __shared__ unsigned short Bs[128 * 64];
  __shared__ float rsum[128][2];

  // ---- capacity-exact XCD supertile decode (32 blocks per supertile) ----
  int bx, by, bz;
  {
    const int i = blockIdx.x;
    const int x0 = i & 7;           // XCD (hw round-robin: id % 8)
    const int j = i >> 3;
    const int p = j & 31;           // position within 32-block supertile
    const int sup = j >> 5;
    const int st = x0 + (sup << 3); // supertile id (bijective)
    if (STORE == ST_QKV) {
      // 3072 blocks; st 0..95 = (xg 0..31, z 0..2). supertile = 8bx x 4by:
      // WS = 8 A-panels (1MB) + 4 W-panels (0.5MB) per XCD L2.
      bz = st >> 5;                       // z: 0=Q,1=K,2=V
      bx = ((st & 31) << 3) + (p & 7);    // 0..255
      by = p >> 3;                        // 0..3
    } else if (STORE == ST_EXP) {
      // 2048 blocks; st 0..63 = (batch, yhalf). WS = Q 1MB + K 1MB.
      bz = st >> 1;
      by = ((st & 1) << 2) + (p >> 3);    // 0..7
      bx = p & 7;                         // 0..7
    } else {
      // 1024 blocks; st 0..31 = batch. WS = E 2MB + V^T 1MB.
      bz = st;
      bx = p & 7;                         // 0..7
      by = p >> 3;                        // 0..3
    }
  }

  const int tid = threadIdx.x;
  const int lane = tid & 63;
  const int wm = tid >> 7;        // 0..1
  const int wn = (tid >> 6) & 1;  // 0..1
  const int cl = lane & 15;
  const int rl = (lane >> 4) * 4;

  const unsigned short* Ag;
  const unsigned short* Bg;
  int lda, ldb, K;
  if (STORE == ST_QKV) {
    Ag = A + (long)(bx * 128) * 512;
    Bg = B + (long)(bz * 512 + by * 128) * 512;
    lda = ldb = 512; K = 512;
  } else if (STORE == ST_EXP) {
    Ag = A + (long)bz * 524288 + (long)(bx * 128) * 512;
    Bg = B + (long)bz * 524288 + (long)(by * 128) * 512;
    lda = ldb = 512; K = 512;
  } else {
    Ag = A + (long)bz * 1048576 + (long)(bx * 128) * 1024;
    Bg = B + (long)bz * 524288 + (long)(by * 128) * 1024;
    lda = ldb = 1024; K = 1024;
  }

  f32x4 acc[4][4];
#pragma unroll
  for (int i = 0; i < 4; ++i)
#pragma unroll
    for (int j = 0; j < 4; ++j) acc[i][j] = (f32x4)(0.0f);

  for (int k0 = 0; k0 < K; k0 += 64) {
#pragma unroll
    for (int it = 0; it < 4; ++it) {
      int c = it * 256 + tid;          // 16B chunk, 1024 per tile
      int row = c >> 3;                // 0..127
      int chk = (c & 7) ^ (row & 7);   // pre-swizzled source chunk
      GLD16(Ag + (long)row * lda + k0 + chk * 8, (char*)As + c * 16);
      GLD16(Bg + (long)row * ldb + k0 + chk * 8, (char*)Bs + c * 16);
    }
    __syncthreads();

#pragma unroll
    for (int kk = 0; kk < 2; ++kk) {
      short8 af[4], bfr[4];
#pragma unroll
      for (int mi = 0; mi < 4; ++mi) {
        int row = wm * 64 + mi * 16 + cl;
        int colb = (((lane >> 4) * 16) + kk * 64) ^ ((row & 7) << 4);
        af[mi] = *(const short8*)((const char*)As + row * 128 + colb);
      }
#pragma unroll
      for (int ni = 0; ni < 4; ++ni) {
        int row = wn * 64 + ni * 16 + cl;
        int colb = (((lane >> 4) * 16) + kk * 64) ^ ((row & 7) << 4);
        bfr[ni] = *(const short8*)((const char*)Bs + row * 128 + colb);
      }
#pragma unroll
      for (int mi = 0; mi < 4; ++mi)
#pragma unroll
        for (int ni = 0; ni < 4; ++ni)
          acc[mi][ni] = __builtin_amdgcn_mfma_f32_16x16x32_bf16(
              af[mi], bfr[ni], acc[mi][ni], 0, 0, 0);
    }
    __syncthreads();
  }

  // ---- epilogues. C/D layout: col = cl, row = rl + r (m89-verified) ----
  if (STORE == ST_QKV) {
    unsigned short* dst = (bz == 0) ? qd : ((bz == 1) ? kd : vd);
    const int rbase = bx * 128 + wm * 64;
    const int cbase = by * 128 + wn * 64;
#pragma unroll
    for (int mi = 0; mi < 4; ++mi)
#pragma unroll
      for (int ni = 0; ni < 4; ++ni)
#pragma unroll
        for (int r = 0; r < 4; ++r) {
          int row = rbase + mi * 16 + rl + r;  // b*1024+s
          int col = cbase + ni * 16 + cl;
          unsigned short v = f2bf(acc[mi][ni][r]);
          if (bz < 2)
            dst[(long)row * 512 + col] = v;
          else  // V^T: [b][d][s]
            dst[(long)(row >> 10) * 524288 + (long)col * 1024 + (row & 1023)] =
                v;
        }
  } else if (STORE == ST_EXP) {
    unsigned short* C = (unsigned short*)Cout + (long)bz * 1048576;
    float rs[4][4];
#pragma unroll
    for (int mi = 0; mi < 4; ++mi)
#pragma unroll
      for (int r = 0; r < 4; ++r) rs[mi][r] = 0.0f;
#pragma unroll
    for (int mi = 0; mi < 4; ++mi)
#pragma unroll
      for (int ni = 0; ni < 4; ++ni)
#pragma unroll
        for (int r = 0; r < 4; ++r) {
          float e = __expf(acc[mi][ni][r]);  // |s| <= ~1.3: no max-sub needed
          rs[mi][r] += e;
          int rowl = wm * 64 + mi * 16 + rl + r;
          int col = by * 128 + wn * 64 + ni * 16 + cl;
          C[(long)(bx * 128 + rowl) * 1024 + col] = f2bf(e);
        }
    // row partial sums: reduce over the 16 cl lanes, then over the 2 wn waves
#pragma unroll
    for (int mi = 0; mi < 4; ++mi)
#pragma unroll
      for (int r = 0; r < 4; ++r) {
#pragma unroll
        for (int off = 1; off < 16; off <<= 1)
          rs[mi][r] += __shfl_xor(rs[mi][r], off, 64);
        if (cl == 0) rsum[wm * 64 + mi * 16 + rl + r][wn] = rs[mi][r];
      }
    __syncthreads();
    if (tid < 128) {
      float s = rsum[tid][0] + rsum[tid][1];
      psum[((long)(bz << 10) + bx * 128 + tid) * 8 + by] = s;
    }
  } else {  // ST_PVN
    float* C = (float*)Cout + (long)bz * 524288;
    float invr[4][4];
#pragma unroll
    for (int mi = 0; mi < 4; ++mi)
#pragma unroll
      for (int r = 0; r < 4; ++r)
        invr[mi][r] =
            invl[(long)(bz << 10) + bx * 128 + wm * 64 + mi * 16 + rl + r];
#pragma unroll
    for (int mi = 0; mi < 4; ++mi)
#pragma unroll
      for (int ni = 0; ni < 4; ++ni)
#pragma unroll
        for (int r = 0; r < 4; ++r) {
          int rowl = wm * 64 + mi * 16 + rl + r;
          int col = by * 128 + wn * 64 + ni * 16 + cl;
          C[(long)(bx * 128 + rowl) * 512 + col] = acc[mi][ni][r] * invr[mi][r];
        }
  }
}

// invl[row] = 1 / sum_{t<8} psum[row][t], 32768 rows.
__global__ __launch_bounds__(256) void invsum(const float* __restrict__ p,
                                              float* __restrict__ inv) {
  const int row = blockIdx.x * 256 + threadIdx.x;
  const float4* q = (const float4*)(p + (long)row * 8);
  float4 a = q[0], b = q[1];
  inv[row] = 1.0f / (a.x + a.y + a.z + a.w + b.x + b.y + b.z + b.w);
}

// Convert x and the three 512x512 weights to bf16 (Wq pre-scaled by 1/sqrt(512)).
__global__ __launch_bounds__(256) void convert_in(
    const float* __restrict__ x, const float* __restrict__ wq,
    const float* __restrict__ wk, const float* __restrict__ wv,
    unsigned short* __restrict__ xb, unsigned short* __restrict__ wb) {
  const long i = (long)blockIdx.x * 256 + threadIdx.x;
  const long NX4 = 16777216 / 4;
  const float* src;
  unsigned short* dst;
  long off;
  float sc = 1.0f;
  if (i < NX4) {
    src = x;
    dst = xb;
    off = i;
  } else {
    long r = i - NX4;
    int w = (int)(r >> 16);
    off = r & 65535;
    src = (w == 0) ? wq : (w == 1) ? wk : wv;
    dst = wb + (long)w * 262144;
    if (w == 0) sc = 0.044194173824159216f;  // 1/sqrt(512)
  }
  float4 f = ((const float4*)src)[off];
  ushort4 o;
  o.x = f2bf(f.x * sc);
  o.y = f2bf(f.y * sc);
  o.z = f2bf(f.z * sc);
  o.w = f2bf(f.w * sc);
  ((ushort4*)dst)[off] = o;
}

extern "C" void kernel_launch(void* const* d_in, const int* in_sizes, int n_in,
                              void* d_out, int out_size, void* d_ws,
                              size_t ws_size, hipStream_t stream) {
  const float* x = (const float*)d_in[0];
  const float* wq = (const float*)d_in[1];
  const float* wk = (const float*)d_in[2];
  const float* wv = (const float*)d_in[3];
  float* out = (float*)d_out;

  unsigned short* xb = (unsigned short*)d_ws;  // 16777216
  unsigned short* wb = xb + 16777216;          // 3*262144 (wq_s|wk|wv)
  unsigned short* qb = wb + 786432;            // 16777216
  unsigned short* kb = qb + 16777216;          // 16777216
  unsigned short* vtb = kb + 16777216;         // 16777216 (V^T [b][d][s])
  unsigned short* sb = vtb + 16777216;         // 33554432 (E = exp(S))
  float* psum = (float*)xb;                    // overlay: xb dead after QKV
  float* invl = psum + 262144;                 // 32768 f32

  convert_in<<<17152, 256, 0, stream>>>(x, wq, wk, wv, xb, wb);

  // Q, K, V^T in one dispatch: M=32768, N=512 each, K=512 (3072 blocks)
  gemm_bt<ST_QKV><<<3072, 256, 0, stream>>>(xb, wb, nullptr, nullptr, nullptr,
                                            qb, kb, vtb);

  // E = exp(Q K^T) per batch + row partial sums (2048 blocks)
  gemm_bt<ST_EXP><<<2048, 256, 0, stream>>>(qb, kb, sb, psum, nullptr, nullptr,
                                            nullptr, nullptr);

  invsum<<<128, 256, 0, stream>>>(psum, invl);

  // out = (E V) * invl : M=1024, N=512, K=1024 per batch (1024 blocks)
  gemm_bt<ST_PVN><<<1024, 256, 0, stream>>>(sb, vtb, out, nullptr, invl,
                                            nullptr, nullptr, nullptr);
}